// Round 6
// baseline (146.682 us; speedup 1.0000x reference)
//
#include <hip/hip_runtime.h>
#include <math.h>

#define BATCH 16
#define CCH 256
#define LSEQ 4096
#define NB 4
#define CB 64
#define MA_H 12
#define BN_EPS 1e-5f

typedef __attribute__((ext_vector_type(8))) short bf16x8;
typedef __attribute__((ext_vector_type(4))) float f32x4;

__device__ inline float b2f(ushort u) {
    union { uint i; float f; } v; v.i = ((uint)u) << 16; return v.f;
}
__device__ inline ushort f2b(float f) {   // round-to-nearest-even
    uint x = __float_as_uint(f);
    return (ushort)((x + 0x7FFFu + ((x >> 16) & 1u)) >> 16);
}

// ---------------------------------------------------------------------------
// Kernel 0: convert fusion weights fp32 [256][512] -> bf16
// ---------------------------------------------------------------------------
__global__ __launch_bounds__(256) void k0_convw(const float* __restrict__ fw,
                                                ushort* __restrict__ wbf)
{
    int i = (blockIdx.x * 256 + threadIdx.x) * 4;
    float4 v = *(const float4*)&fw[i];
    ushort4 o;
    o.x = f2b(v.x); o.y = f2b(v.y); o.z = f2b(v.z); o.w = f2b(v.w);
    *(ushort4*)&wbf[i] = o;
}

// ---------------------------------------------------------------------------
// Kernel 0b: reorder branch conv weights [br][o][i][kk] fp32
//            -> wbr[br][o][kk*64+i] bf16  (K-major for MFMA B fragments)
// ---------------------------------------------------------------------------
__global__ __launch_bounds__(256) void k0b_convw_branch(
    const float* __restrict__ conv_w, ushort* __restrict__ wbr)
{
    int e = blockIdx.x * 256 + threadIdx.x;     // 4*64*3*64 = 49152
    int i    = e & 63;
    int rest = e >> 6;            // br*192 + o*3 + kk  (0..767)
    int kk   = rest % 3;
    int orow = rest / 3;          // br*64 + o  (0..255)
    float v = conv_w[(size_t)orow * 192 + i * 3 + kk];
    wbr[(size_t)orow * 192 + kk * 64 + i] = f2b(v);
}

// ---------------------------------------------------------------------------
// Kernel 0c: transpose x [B][C][L] fp32 -> xT [B][L][C] bf16
// block: 64 pos x 256 ch for one batch; grid (64, 16)
// LDS [ch][66 ushort] (uint-packed); column reads lane-stride 33 dw = bank+1
// ---------------------------------------------------------------------------
__global__ __launch_bounds__(256) void k0c_xT(const float* __restrict__ x,
                                              ushort* __restrict__ xT)
{
    const int p0    = blockIdx.x * 64;
    const int batch = blockIdx.y;
    const int tid   = threadIdx.x;

    __shared__ uint ls[256 * 33];        // [ch][33 uint] = [ch][66 ushort]

    const float* xb = x + (size_t)batch * CCH * LSEQ;
#pragma unroll
    for (int pass = 0; pass < 16; ++pass) {
        int e  = tid + pass * 256;       // 256 ch x 16 chunks
        int ch = e >> 4;
        int c4 = e & 15;
        float4 v = *(const float4*)&xb[(size_t)ch * LSEQ + p0 + c4 * 4];
        uint u0 = (uint)f2b(v.x) | ((uint)f2b(v.y) << 16);
        uint u1 = (uint)f2b(v.z) | ((uint)f2b(v.w) << 16);
        ls[ch * 33 + c4 * 2]     = u0;
        ls[ch * 33 + c4 * 2 + 1] = u1;
    }
    __syncthreads();

    const int w = tid >> 6, l = tid & 63;
    const ushort* lsu = (const ushort*)ls;
    ushort* dst = xT + ((size_t)batch * LSEQ + p0) * CCH;
#pragma unroll
    for (int r = 0; r < 16; ++r) {
        int p = w * 16 + r;
#pragma unroll
        for (int q = 0; q < 4; ++q) {
            int ch = l + 64 * q;                     // lane-stride 66 ushort = 33 dw
            dst[(size_t)p * CCH + ch] = lsu[ch * 66 + p];
        }
    }
}

// ---------------------------------------------------------------------------
// Kernel 1: per-branch dilated conv(k=3) as bf16 MFMA GEMM + BN + exact GELU
// A-tile staged [pos][ch] via LINEAR uint4 loads from xT (k-contig frags)
// grid (32 posTiles of 128, 4 branches, 16 batch), block 256 (4 waves)
// ---------------------------------------------------------------------------
#define SXA 72     // LDS stride for x-tile rows (144B, 16B-aligned)
#define SWB 200    // LDS stride for w rows (400B, 16B-aligned)
__global__ __launch_bounds__(256) void k1_conv_mfma(
    const ushort* __restrict__ xT, const ushort* __restrict__ wbr,
    const float* __restrict__ conv_b, const float* __restrict__ bn_gamma,
    const float* __restrict__ bn_beta, const float* __restrict__ bn_mean,
    const float* __restrict__ bn_var, ushort* __restrict__ h)
{
    const int tile  = blockIdx.x;
    const int br    = blockIdx.y;
    const int batch = blockIdx.z;
    const int d     = 1 << br;
    const int t0    = tile * 128;
    const int tid   = threadIdx.x;
    const int wm    = tid >> 6;      // wave -> pos quarter (32 pos)
    const int lane  = tid & 63;
    const int lo    = lane & 15;
    const int hi    = lane >> 4;

    __shared__ ushort xsA[144 * SXA];   // x^T tile: [local pos 0..143][64 ch]
    __shared__ ushort wlB[64 * SWB];    // w tile:   [64 o][192 k]

    // ---- stage A: linear uint4 rows from xT, zero-pad outside [0,L) ----
    {
        const ushort* xTb = xT + (size_t)batch * LSEQ * CCH + br * CB;
#pragma unroll
        for (int pass = 0; pass < 5; ++pass) {
            int e = tid + pass * 256;
            int p = e >> 3;                 // 0..159
            int c = e & 7;                  // 8 x 16B per 128B row
            if (p < 144) {
                int gp = t0 - 8 + p;
                uint4 v = make_uint4(0u, 0u, 0u, 0u);
                if (gp >= 0 && gp < LSEQ)
                    v = *(const uint4*)&xTb[(size_t)gp * CCH + c * 8];
                *(uint4*)&xsA[p * SXA + c * 8] = v;
            }
        }
    }
    // ---- stage B: linear coalesced uint4; wlB[o][192] padded ----
    {
        const ushort* wrow = wbr + ((size_t)br * CB) * 192;
#pragma unroll
        for (int pass = 0; pass < 6; ++pass) {
            int e = tid + pass * 256;           // < 64*24
            int o = e / 24;
            int c = e - o * 24;
            uint4 v = *(const uint4*)&wrow[e * 8];
            *(uint4*)&wlB[o * SWB + c * 8] = v;
        }
    }
    __syncthreads();

    f32x4 acc[2][4];
#pragma unroll
    for (int mi = 0; mi < 2; ++mi)
#pragma unroll
        for (int ni = 0; ni < 4; ++ni) acc[mi][ni] = (f32x4)0.f;

#pragma unroll
    for (int kk = 0; kk < 3; ++kk) {
        const int roff = 8 + (kk - 1) * d;          // 0..16
#pragma unroll
        for (int ks = 0; ks < 2; ++ks) {
            bf16x8 af[2], bfr[4];
#pragma unroll
            for (int mi = 0; mi < 2; ++mi)
                af[mi] = *(const bf16x8*)&xsA[
                    (wm * 32 + mi * 16 + lo + roff) * SXA + ks * 32 + hi * 8];
#pragma unroll
            for (int ni = 0; ni < 4; ++ni)
                bfr[ni] = *(const bf16x8*)&wlB[
                    (ni * 16 + lo) * SWB + kk * 64 + ks * 32 + hi * 8];
#pragma unroll
            for (int mi = 0; mi < 2; ++mi)
#pragma unroll
                for (int ni = 0; ni < 4; ++ni)
                    acc[mi][ni] = __builtin_amdgcn_mfma_f32_16x16x32_bf16(
                        af[mi], bfr[ni], acc[mi][ni], 0, 0, 0);
        }
    }

    // ---- epilogue: bias + BN + exact GELU -> h bf16 [B][C][L] ----
    ushort* hbase = h + ((size_t)(batch * CCH + br * CB)) * LSEQ;
#pragma unroll
    for (int ni = 0; ni < 4; ++ni) {
        const int o  = ni * 16 + lo;
        const int go = br * CB + o;
        float bias = conv_b[go];
        float inv  = rsqrtf(bn_var[go] + BN_EPS);
        float sc   = bn_gamma[go] * inv;
        float sh   = bn_beta[go] - bn_mean[go] * sc;
#pragma unroll
        for (int mi = 0; mi < 2; ++mi) {
            const int pos = t0 + wm * 32 + mi * 16 + hi * 4;
            ushort4 ov;
            ushort* po = (ushort*)&ov;
#pragma unroll
            for (int q = 0; q < 4; ++q) {
                float v = acc[mi][ni][q] + bias;
                v = v * sc + sh;
                po[q] = f2b(0.5f * v * (1.f + erff(v * 0.70710678118654752f)));
            }
            *(ushort4*)&hbase[(size_t)o * LSEQ + pos] = ov;
        }
    }
}

// ---------------------------------------------------------------------------
// Kernel 2: 25-tap edge-padded MA -> long; short = h - long; branch cumsum;
// writes TRANSPOSED fusedT[b][pos][512] bf16 (MFMA B-operand needs K-contig)
// grid (64 posTiles of 64, 1, 16 batch), block 256
// ---------------------------------------------------------------------------
#define HS_W 92        // 88 used + pad (184B rows: 8B-aligned, <=4-way banks)
__global__ __launch_bounds__(256) void k2_ma_fuse(
    const ushort* __restrict__ h, ushort* __restrict__ fusedT)
{
    const int t0    = blockIdx.x * 64;
    const int batch = blockIdx.z;
    const int tid   = threadIdx.x;

    __shared__ ushort hs[256][HS_W];

    for (int e = tid; e < 256 * 22; e += 256) {
        int row = e / 22;
        int c4  = e - row * 22;
        int gt0 = t0 - MA_H + c4 * 4;
        const ushort* src = h + ((size_t)(batch * CCH + row)) * LSEQ;
        ushort4 v;
        if (gt0 >= 0 && gt0 + 3 < LSEQ) {
            v = *(const ushort4*)&src[gt0];
        } else {
            ushort* pv = (ushort*)&v;
#pragma unroll
            for (int q = 0; q < 4; ++q) {
                int gt = gt0 + q;
                gt = max(0, min(LSEQ - 1, gt));
                pv[q] = src[gt];
            }
        }
        *(ushort4*)&hs[row][c4 * 4] = v;
    }
    __syncthreads();

    const int j  = tid & 63;
    const int pg = tid >> 6;
    const float inv25 = 1.f / 25.f;

#pragma unroll
    for (int p4 = 0; p4 < 4; ++p4) {
        const int p0 = pg * 16 + p4 * 4;
        float sarr[NB][4], larr[NB][4];
#pragma unroll
        for (int br = 0; br < NB; ++br) {
            const int c = br * CB + j;
            float r[28];
#pragma unroll
            for (int q = 0; q < 7; ++q) {
                ushort4 v = *(const ushort4*)&hs[c][p0 + q * 4];
                r[q * 4 + 0] = b2f(v.x); r[q * 4 + 1] = b2f(v.y);
                r[q * 4 + 2] = b2f(v.z); r[q * 4 + 3] = b2f(v.w);
            }
            float s = 0.f;
#pragma unroll
            for (int q = 0; q < 25; ++q) s += r[q];
            float l0 = s;
            float l1 = l0 - r[0] + r[25];
            float l2 = l1 - r[1] + r[26];
            float l3 = l2 - r[2] + r[27];
            larr[br][0] = l0 * inv25; larr[br][1] = l1 * inv25;
            larr[br][2] = l2 * inv25; larr[br][3] = l3 * inv25;
#pragma unroll
            for (int q = 0; q < 4; ++q) sarr[br][q] = r[q + 12] - larr[br][q];
        }
#pragma unroll
        for (int b2 = 1; b2 < NB; ++b2)
#pragma unroll
            for (int q = 0; q < 4; ++q) sarr[b2][q] += sarr[b2 - 1][q];
#pragma unroll
        for (int b2 = NB - 2; b2 >= 0; --b2)
#pragma unroll
            for (int q = 0; q < 4; ++q) larr[b2][q] += larr[b2 + 1][q];

#pragma unroll
        for (int q = 0; q < 4; ++q) {
            const int pos = t0 + p0 + q;
            ushort* dst = fusedT + ((size_t)(batch * LSEQ + pos)) * (2 * CCH);
#pragma unroll
            for (int b2 = 0; b2 < NB; ++b2) {
                dst[b2 * CB + j]       = f2b(sarr[b2][q]);
                dst[CCH + b2 * CB + j] = f2b(larr[b2][q]);
            }
        }
    }
}

// ---------------------------------------------------------------------------
// Kernel 3: fusion 1x1 conv as bf16 MFMA GEMM + bias + ReLU + alpha*x
// ---------------------------------------------------------------------------
#define KTOT 512
#define SA 72
__global__ __launch_bounds__(256) void k3_fusion(
    const ushort* __restrict__ fusedT, const ushort* __restrict__ wbf,
    const float* __restrict__ fb, const float* __restrict__ x,
    const float* __restrict__ alpha, float* __restrict__ out)
{
    const int t0    = blockIdx.x * 128;
    const int oBase = blockIdx.y * 128;
    const int batch = blockIdx.z;
    const int tid   = threadIdx.x;
    const int wid   = tid >> 6;
    const int lane  = tid & 63;
    const int lo    = lane & 15;
    const int hi    = lane >> 4;
    const int wm    = wid >> 1;
    const int wn    = wid & 1;

    __shared__ short AL[128 * SA];
    __shared__ short WL[128 * SA];

    f32x4 acc[4][4];
#pragma unroll
    for (int mi = 0; mi < 4; ++mi)
#pragma unroll
        for (int ni = 0; ni < 4; ++ni) acc[mi][ni] = (f32x4)0.f;

    const int srow = tid >> 3;
    const int scol = tid & 7;

    for (int k0 = 0; k0 < KTOT; k0 += 64) {
        __syncthreads();
#pragma unroll
        for (int pass = 0; pass < 4; ++pass) {
            int row = pass * 32 + srow;
            uint4 va = *(const uint4*)&fusedT[
                ((size_t)(batch * LSEQ + t0 + row)) * (2 * CCH) + k0 + scol * 8];
            *(uint4*)&AL[row * SA + scol * 8] = va;
            uint4 vw = *(const uint4*)&wbf[
                (size_t)(oBase + row) * KTOT + k0 + scol * 8];
            *(uint4*)&WL[row * SA + scol * 8] = vw;
        }
        __syncthreads();

#pragma unroll
        for (int ks = 0; ks < 2; ++ks) {
            bf16x8 af[4], bfr[4];
#pragma unroll
            for (int mi = 0; mi < 4; ++mi)
                af[mi] = *(const bf16x8*)&AL[(wm * 64 + mi * 16 + lo) * SA + ks * 32 + hi * 8];
#pragma unroll
            for (int ni = 0; ni < 4; ++ni)
                bfr[ni] = *(const bf16x8*)&WL[(wn * 64 + ni * 16 + lo) * SA + ks * 32 + hi * 8];
#pragma unroll
            for (int mi = 0; mi < 4; ++mi)
#pragma unroll
                for (int ni = 0; ni < 4; ++ni)
                    acc[mi][ni] = __builtin_amdgcn_mfma_f32_16x16x32_bf16(
                        af[mi], bfr[ni], acc[mi][ni], 0, 0, 0);
        }
    }

    const float al = alpha[0];
#pragma unroll
    for (int ni = 0; ni < 4; ++ni) {
        const int o = oBase + wn * 64 + ni * 16 + lo;
        const float bias = fb[o];
#pragma unroll
        for (int mi = 0; mi < 4; ++mi) {
            const int pos = t0 + wm * 64 + mi * 16 + hi * 4;
            size_t base = ((size_t)(batch * CCH + o)) * LSEQ + pos;
            float4 xv = *(const float4*)&x[base];
            float4 ov;
            ov.x = fmaxf(acc[mi][ni][0] + bias, 0.f) + al * xv.x;
            ov.y = fmaxf(acc[mi][ni][1] + bias, 0.f) + al * xv.y;
            ov.z = fmaxf(acc[mi][ni][2] + bias, 0.f) + al * xv.z;
            ov.w = fmaxf(acc[mi][ni][3] + bias, 0.f) + al * xv.w;
            *(float4*)&out[base] = ov;
        }
    }
}

// ---------------------------------------------------------------------------
extern "C" void kernel_launch(void* const* d_in, const int* in_sizes, int n_in,
                              void* d_out, int out_size, void* d_ws, size_t ws_size,
                              hipStream_t stream)
{
    const float* x        = (const float*)d_in[0];
    const float* conv_w   = (const float*)d_in[1];
    const float* conv_b   = (const float*)d_in[2];
    const float* bn_gamma = (const float*)d_in[3];
    const float* bn_beta  = (const float*)d_in[4];
    const float* bn_mean  = (const float*)d_in[5];
    const float* bn_var   = (const float*)d_in[6];
    const float* fw       = (const float*)d_in[7];
    const float* fb       = (const float*)d_in[8];
    const float* alpha    = (const float*)d_in[9];
    float* out = (float*)d_out;

    ushort* h      = (ushort*)d_ws;                                      // 32 MiB
    ushort* fusedT = (ushort*)((char*)d_ws + (size_t)32 * 1024 * 1024);  // 64 MiB
    ushort* wbf    = (ushort*)((char*)d_ws + (size_t)96 * 1024 * 1024);  // 256 KiB
    ushort* wbr    = (ushort*)((char*)d_ws + (size_t)97 * 1024 * 1024);  // 96 KiB
    ushort* xT     = (ushort*)((char*)d_ws + (size_t)98 * 1024 * 1024);  // 32 MiB

    k0_convw<<<dim3(128), 256, 0, stream>>>(fw, wbf);
    k0b_convw_branch<<<dim3(192), 256, 0, stream>>>(conv_w, wbr);
    k0c_xT<<<dim3(64, 16), 256, 0, stream>>>(x, xT);

    dim3 g1(32, NB, BATCH);
    k1_conv_mfma<<<g1, 256, 0, stream>>>(xT, wbr, conv_b, bn_gamma, bn_beta,
                                         bn_mean, bn_var, h);
    dim3 g2(64, 1, BATCH);
    k2_ma_fuse<<<g2, 256, 0, stream>>>(h, fusedT);

    dim3 g3(32, 2, BATCH);
    k3_fusion<<<g3, 256, 0, stream>>>(fusedT, wbf, fb, x, alpha, out);
}

// Round 8
// 144.322 us; speedup vs baseline: 1.0164x; 1.0164x over previous
//
#include <hip/hip_runtime.h>
#include <math.h>

#define BATCH 16
#define CCH 256
#define LSEQ 4096
#define NB 4
#define CB 64
#define MA_H 12
#define BN_EPS 1e-5f

typedef __attribute__((ext_vector_type(8))) short bf16x8;
typedef __attribute__((ext_vector_type(4))) float f32x4;

__device__ inline float b2f(ushort u) {
    union { uint i; float f; } v; v.i = ((uint)u) << 16; return v.f;
}
__device__ inline ushort f2b(float f) {   // round-to-nearest-even
    uint x = __float_as_uint(f);
    return (ushort)((x + 0x7FFFu + ((x >> 16) & 1u)) >> 16);
}

// ---------------------------------------------------------------------------
// Kernel 0: convert fusion weights fp32 [256][512] -> bf16
// ---------------------------------------------------------------------------
__global__ __launch_bounds__(256) void k0_convw(const float* __restrict__ fw,
                                                ushort* __restrict__ wbf)
{
    int i = (blockIdx.x * 256 + threadIdx.x) * 4;
    float4 v = *(const float4*)&fw[i];
    ushort4 o;
    o.x = f2b(v.x); o.y = f2b(v.y); o.z = f2b(v.z); o.w = f2b(v.w);
    *(ushort4*)&wbf[i] = o;
}

// ---------------------------------------------------------------------------
// Kernel 0b: reorder branch conv weights [br][o][i][kk] fp32
//            -> wbr[br][o][kk*64+i] bf16  (K-major for MFMA B fragments)
// ---------------------------------------------------------------------------
__global__ __launch_bounds__(256) void k0b_convw_branch(
    const float* __restrict__ conv_w, ushort* __restrict__ wbr)
{
    int e = blockIdx.x * 256 + threadIdx.x;     // 4*64*3*64 = 49152
    int i    = e & 63;
    int rest = e >> 6;            // br*192 + o*3 + kk  (0..767)
    int kk   = rest % 3;
    int orow = rest / 3;          // br*64 + o  (0..255)
    float v = conv_w[(size_t)orow * 192 + i * 3 + kk];
    wbr[(size_t)orow * 192 + kk * 64 + i] = f2b(v);
}

// ---------------------------------------------------------------------------
// Kernel 0c: transpose x [B][C][L] fp32 -> xT [B][L][C] bf16
// ---------------------------------------------------------------------------
__global__ __launch_bounds__(256) void k0c_xT(const float* __restrict__ x,
                                              ushort* __restrict__ xT)
{
    const int p0    = blockIdx.x * 64;
    const int batch = blockIdx.y;
    const int tid   = threadIdx.x;

    __shared__ uint ls[256 * 33];        // [ch][33 uint] = [ch][66 ushort]

    const float* xb = x + (size_t)batch * CCH * LSEQ;
#pragma unroll
    for (int pass = 0; pass < 16; ++pass) {
        int e  = tid + pass * 256;       // 256 ch x 16 chunks
        int ch = e >> 4;
        int c4 = e & 15;
        float4 v = *(const float4*)&xb[(size_t)ch * LSEQ + p0 + c4 * 4];
        uint u0 = (uint)f2b(v.x) | ((uint)f2b(v.y) << 16);
        uint u1 = (uint)f2b(v.z) | ((uint)f2b(v.w) << 16);
        ls[ch * 33 + c4 * 2]     = u0;
        ls[ch * 33 + c4 * 2 + 1] = u1;
    }
    __syncthreads();

    const int w = tid >> 6, l = tid & 63;
    const ushort* lsu = (const ushort*)ls;
    ushort* dst = xT + ((size_t)batch * LSEQ + p0) * CCH;
#pragma unroll
    for (int r = 0; r < 16; ++r) {
        int p = w * 16 + r;
#pragma unroll
        for (int q = 0; q < 4; ++q) {
            int ch = l + 64 * q;                     // lane-stride 66 ushort = 33 dw
            dst[(size_t)p * CCH + ch] = lsu[ch * 66 + p];
        }
    }
}

// ---------------------------------------------------------------------------
// Kernel 1: per-branch dilated conv(k=3) as bf16 MFMA GEMM + BN + exact GELU
// ---------------------------------------------------------------------------
#define SXA 72     // LDS stride for x-tile rows (144B, 16B-aligned)
#define SWB 200    // LDS stride for w rows (400B, 16B-aligned)
__global__ __launch_bounds__(256) void k1_conv_mfma(
    const ushort* __restrict__ xT, const ushort* __restrict__ wbr,
    const float* __restrict__ conv_b, const float* __restrict__ bn_gamma,
    const float* __restrict__ bn_beta, const float* __restrict__ bn_mean,
    const float* __restrict__ bn_var, ushort* __restrict__ h)
{
    const int tile  = blockIdx.x;
    const int br    = blockIdx.y;
    const int batch = blockIdx.z;
    const int d     = 1 << br;
    const int t0    = tile * 128;
    const int tid   = threadIdx.x;
    const int wm    = tid >> 6;
    const int lane  = tid & 63;
    const int lo    = lane & 15;
    const int hi    = lane >> 4;

    __shared__ ushort xsA[144 * SXA];
    __shared__ ushort wlB[64 * SWB];

    {
        const ushort* xTb = xT + (size_t)batch * LSEQ * CCH + br * CB;
#pragma unroll
        for (int pass = 0; pass < 5; ++pass) {
            int e = tid + pass * 256;
            int p = e >> 3;
            int c = e & 7;
            if (p < 144) {
                int gp = t0 - 8 + p;
                uint4 v = make_uint4(0u, 0u, 0u, 0u);
                if (gp >= 0 && gp < LSEQ)
                    v = *(const uint4*)&xTb[(size_t)gp * CCH + c * 8];
                *(uint4*)&xsA[p * SXA + c * 8] = v;
            }
        }
    }
    {
        const ushort* wrow = wbr + ((size_t)br * CB) * 192;
#pragma unroll
        for (int pass = 0; pass < 6; ++pass) {
            int e = tid + pass * 256;
            int o = e / 24;
            int c = e - o * 24;
            uint4 v = *(const uint4*)&wrow[e * 8];
            *(uint4*)&wlB[o * SWB + c * 8] = v;
        }
    }
    __syncthreads();

    f32x4 acc[2][4];
#pragma unroll
    for (int mi = 0; mi < 2; ++mi)
#pragma unroll
        for (int ni = 0; ni < 4; ++ni) acc[mi][ni] = (f32x4)0.f;

#pragma unroll
    for (int kk = 0; kk < 3; ++kk) {
        const int roff = 8 + (kk - 1) * d;
#pragma unroll
        for (int ks = 0; ks < 2; ++ks) {
            bf16x8 af[2], bfr[4];
#pragma unroll
            for (int mi = 0; mi < 2; ++mi)
                af[mi] = *(const bf16x8*)&xsA[
                    (wm * 32 + mi * 16 + lo + roff) * SXA + ks * 32 + hi * 8];
#pragma unroll
            for (int ni = 0; ni < 4; ++ni)
                bfr[ni] = *(const bf16x8*)&wlB[
                    (ni * 16 + lo) * SWB + kk * 64 + ks * 32 + hi * 8];
#pragma unroll
            for (int mi = 0; mi < 2; ++mi)
#pragma unroll
                for (int ni = 0; ni < 4; ++ni)
                    acc[mi][ni] = __builtin_amdgcn_mfma_f32_16x16x32_bf16(
                        af[mi], bfr[ni], acc[mi][ni], 0, 0, 0);
        }
    }

    ushort* hbase = h + ((size_t)(batch * CCH + br * CB)) * LSEQ;
#pragma unroll
    for (int ni = 0; ni < 4; ++ni) {
        const int o  = ni * 16 + lo;
        const int go = br * CB + o;
        float bias = conv_b[go];
        float inv  = rsqrtf(bn_var[go] + BN_EPS);
        float sc   = bn_gamma[go] * inv;
        float sh   = bn_beta[go] - bn_mean[go] * sc;
#pragma unroll
        for (int mi = 0; mi < 2; ++mi) {
            const int pos = t0 + wm * 32 + mi * 16 + hi * 4;
            ushort4 ov;
            ushort* po = (ushort*)&ov;
#pragma unroll
            for (int q = 0; q < 4; ++q) {
                float v = acc[mi][ni][q] + bias;
                v = v * sc + sh;
                po[q] = f2b(0.5f * v * (1.f + erff(v * 0.70710678118654752f)));
            }
            *(ushort4*)&hbase[(size_t)o * LSEQ + pos] = ov;
        }
    }
}

// ---------------------------------------------------------------------------
// Kernel 2: 25-tap edge-padded MA -> long; short = h - long; branch cumsum.
// Outputs go through an LDS transpose tile (os) so global stores are
// full-row 16B/lane coalesced (was: 128 scalar 2B stores per thread).
// grid (64 posTiles of 64, 1, 16 batch), block 256
// ---------------------------------------------------------------------------
#define HS_W 94    // lane stride 47 dw, gcd(47,32)=1 -> conflict-free reads
__global__ __launch_bounds__(256) void k2_ma_fuse(
    const ushort* __restrict__ h, ushort* __restrict__ fusedT)
{
    const int t0    = blockIdx.x * 64;
    const int batch = blockIdx.z;
    const int tid   = threadIdx.x;

    __shared__ ushort hs[256][HS_W];     // 48128 B
    __shared__ ushort os[16][2 * CCH];   // 16384 B transpose tile

    for (int e = tid; e < 256 * 22; e += 256) {
        int row = e / 22;
        int c4  = e - row * 22;
        int gt0 = t0 - MA_H + c4 * 4;
        const ushort* src = h + ((size_t)(batch * CCH + row)) * LSEQ;
        ushort4 v;
        if (gt0 >= 0 && gt0 + 3 < LSEQ) {
            v = *(const ushort4*)&src[gt0];
        } else {
            ushort* pv = (ushort*)&v;
#pragma unroll
            for (int q = 0; q < 4; ++q) {
                int gt = gt0 + q;
                gt = max(0, min(LSEQ - 1, gt));
                pv[q] = src[gt];
            }
        }
        *(ushort4*)&hs[row][c4 * 4] = v;
    }
    __syncthreads();

    const int j  = tid & 63;
    const int pg = tid >> 6;
    const float inv25 = 1.f / 25.f;

#pragma unroll
    for (int p4 = 0; p4 < 4; ++p4) {
        const int p0 = pg * 16 + p4 * 4;
        float sarr[NB][4], larr[NB][4];
#pragma unroll
        for (int br = 0; br < NB; ++br) {
            const int c = br * CB + j;
            float r[28];
#pragma unroll
            for (int q = 0; q < 7; ++q) {
                ushort4 v = *(const ushort4*)&hs[c][p0 + q * 4];
                r[q * 4 + 0] = b2f(v.x); r[q * 4 + 1] = b2f(v.y);
                r[q * 4 + 2] = b2f(v.z); r[q * 4 + 3] = b2f(v.w);
            }
            float s = 0.f;
#pragma unroll
            for (int q = 0; q < 25; ++q) s += r[q];
            float l0 = s;
            float l1 = l0 - r[0] + r[25];
            float l2 = l1 - r[1] + r[26];
            float l3 = l2 - r[2] + r[27];
            larr[br][0] = l0 * inv25; larr[br][1] = l1 * inv25;
            larr[br][2] = l2 * inv25; larr[br][3] = l3 * inv25;
#pragma unroll
            for (int q = 0; q < 4; ++q) sarr[br][q] = r[q + 12] - larr[br][q];
        }
#pragma unroll
        for (int b2 = 1; b2 < NB; ++b2)
#pragma unroll
            for (int q = 0; q < 4; ++q) sarr[b2][q] += sarr[b2 - 1][q];
#pragma unroll
        for (int b2 = NB - 2; b2 >= 0; --b2)
#pragma unroll
            for (int q = 0; q < 4; ++q) larr[b2][q] += larr[b2 + 1][q];

        if (p4) __syncthreads();         // prior os drain complete
#pragma unroll
        for (int q = 0; q < 4; ++q) {
            const int r = pg * 4 + q;    // os row
#pragma unroll
            for (int b2 = 0; b2 < NB; ++b2) {
                os[r][b2 * CB + j]       = f2b(sarr[b2][q]);
                os[r][CCH + b2 * CB + j] = f2b(larr[b2][q]);
            }
        }
        __syncthreads();
        // drain os: one wave per row, 1024B contiguous per instruction
#pragma unroll
        for (int n = 0; n < 4; ++n) {
            int e = tid + n * 256;
            int r = e >> 6;              // 0..15
            int c = e & 63;              // uint4 index within row
            int pos = t0 + (r >> 2) * 16 + p4 * 4 + (r & 3);
            *(uint4*)&fusedT[((size_t)(batch * LSEQ + pos)) * (2 * CCH) + c * 8] =
                *(const uint4*)&os[r][c * 8];
        }
    }
}

// ---------------------------------------------------------------------------
// Kernel 3: fusion 1x1 conv as bf16 MFMA GEMM + bias + ReLU + alpha*x
// ---------------------------------------------------------------------------
#define KTOT 512
#define SA 72
__global__ __launch_bounds__(256) void k3_fusion(
    const ushort* __restrict__ fusedT, const ushort* __restrict__ wbf,
    const float* __restrict__ fb, const float* __restrict__ x,
    const float* __restrict__ alpha, float* __restrict__ out)
{
    const int t0    = blockIdx.x * 128;
    const int oBase = blockIdx.y * 128;
    const int batch = blockIdx.z;
    const int tid   = threadIdx.x;
    const int wid   = tid >> 6;
    const int lane  = tid & 63;
    const int lo    = lane & 15;
    const int hi    = lane >> 4;
    const int wm    = wid >> 1;
    const int wn    = wid & 1;

    __shared__ short AL[128 * SA];
    __shared__ short WL[128 * SA];

    f32x4 acc[4][4];
#pragma unroll
    for (int mi = 0; mi < 4; ++mi)
#pragma unroll
        for (int ni = 0; ni < 4; ++ni) acc[mi][ni] = (f32x4)0.f;

    const int srow = tid >> 3;
    const int scol = tid & 7;

    for (int k0 = 0; k0 < KTOT; k0 += 64) {
        __syncthreads();
#pragma unroll
        for (int pass = 0; pass < 4; ++pass) {
            int row = pass * 32 + srow;
            uint4 va = *(const uint4*)&fusedT[
                ((size_t)(batch * LSEQ + t0 + row)) * (2 * CCH) + k0 + scol * 8];
            *(uint4*)&AL[row * SA + scol * 8] = va;
            uint4 vw = *(const uint4*)&wbf[
                (size_t)(oBase + row) * KTOT + k0 + scol * 8];
            *(uint4*)&WL[row * SA + scol * 8] = vw;
        }
        __syncthreads();

#pragma unroll
        for (int ks = 0; ks < 2; ++ks) {
            bf16x8 af[4], bfr[4];
#pragma unroll
            for (int mi = 0; mi < 4; ++mi)
                af[mi] = *(const bf16x8*)&AL[(wm * 64 + mi * 16 + lo) * SA + ks * 32 + hi * 8];
#pragma unroll
            for (int ni = 0; ni < 4; ++ni)
                bfr[ni] = *(const bf16x8*)&WL[(wn * 64 + ni * 16 + lo) * SA + ks * 32 + hi * 8];
#pragma unroll
            for (int mi = 0; mi < 4; ++mi)
#pragma unroll
                for (int ni = 0; ni < 4; ++ni)
                    acc[mi][ni] = __builtin_amdgcn_mfma_f32_16x16x32_bf16(
                        af[mi], bfr[ni], acc[mi][ni], 0, 0, 0);
        }
    }

    const float al = alpha[0];
#pragma unroll
    for (int ni = 0; ni < 4; ++ni) {
        const int o = oBase + wn * 64 + ni * 16 + lo;
        const float bias = fb[o];
#pragma unroll
        for (int mi = 0; mi < 4; ++mi) {
            const int pos = t0 + wm * 64 + mi * 16 + hi * 4;
            size_t base = ((size_t)(batch * CCH + o)) * LSEQ + pos;
            float4 xv = *(const float4*)&x[base];
            float4 ov;
            ov.x = fmaxf(acc[mi][ni][0] + bias, 0.f) + al * xv.x;
            ov.y = fmaxf(acc[mi][ni][1] + bias, 0.f) + al * xv.y;
            ov.z = fmaxf(acc[mi][ni][2] + bias, 0.f) + al * xv.z;
            ov.w = fmaxf(acc[mi][ni][3] + bias, 0.f) + al * xv.w;
            *(float4*)&out[base] = ov;
        }
    }
}

// ---------------------------------------------------------------------------
extern "C" void kernel_launch(void* const* d_in, const int* in_sizes, int n_in,
                              void* d_out, int out_size, void* d_ws, size_t ws_size,
                              hipStream_t stream)
{
    const float* x        = (const float*)d_in[0];
    const float* conv_w   = (const float*)d_in[1];
    const float* conv_b   = (const float*)d_in[2];
    const float* bn_gamma = (const float*)d_in[3];
    const float* bn_beta  = (const float*)d_in[4];
    const float* bn_mean  = (const float*)d_in[5];
    const float* bn_var   = (const float*)d_in[6];
    const float* fw       = (const float*)d_in[7];
    const float* fb       = (const float*)d_in[8];
    const float* alpha    = (const float*)d_in[9];
    float* out = (float*)d_out;

    ushort* h      = (ushort*)d_ws;                                      // 32 MiB
    ushort* fusedT = (ushort*)((char*)d_ws + (size_t)32 * 1024 * 1024);  // 64 MiB
    ushort* wbf    = (ushort*)((char*)d_ws + (size_t)96 * 1024 * 1024);  // 256 KiB
    ushort* wbr    = (ushort*)((char*)d_ws + (size_t)97 * 1024 * 1024);  // 96 KiB
    ushort* xT     = (ushort*)((char*)d_ws + (size_t)98 * 1024 * 1024);  // 32 MiB

    k0_convw<<<dim3(128), 256, 0, stream>>>(fw, wbf);
    k0b_convw_branch<<<dim3(192), 256, 0, stream>>>(conv_w, wbr);
    k0c_xT<<<dim3(64, 16), 256, 0, stream>>>(x, xT);

    dim3 g1(32, NB, BATCH);
    k1_conv_mfma<<<g1, 256, 0, stream>>>(xT, wbr, conv_b, bn_gamma, bn_beta,
                                         bn_mean, bn_var, h);
    dim3 g2(64, 1, BATCH);
    k2_ma_fuse<<<g2, 256, 0, stream>>>(h, fusedT);

    dim3 g3(32, 2, BATCH);
    k3_fusion<<<g3, 256, 0, stream>>>(fusedT, wbf, fb, x, alpha, out);
}

// Round 9
// 114.026 us; speedup vs baseline: 1.2864x; 1.2657x over previous
//
#include <hip/hip_runtime.h>
#include <math.h>

#define BATCH 16
#define CCH 256
#define LSEQ 4096
#define NB 4
#define CB 64
#define MA_H 12
#define BN_EPS 1e-5f

typedef __attribute__((ext_vector_type(8))) short bf16x8;
typedef __attribute__((ext_vector_type(4))) float f32x4;

__device__ inline float b2f(ushort u) {
    union { uint i; float f; } v; v.i = ((uint)u) << 16; return v.f;
}
__device__ inline ushort f2b(float f) {   // round-to-nearest-even
    uint x = __float_as_uint(f);
    return (ushort)((x + 0x7FFFu + ((x >> 16) & 1u)) >> 16);
}

// ---------------------------------------------------------------------------
// Kernel 0w: fold the branch cumsum into the fusion weights.
// wbf2[o][c]      = SUM_{b2>=br} fw[o][b2*64+j]            (c = br*64+j)
// wbf2[o][256+c]  = SUM_{b2<=br} fw[o][256+b2*64+j] - above
// out = SUM_c h[c]*wbf2[.][c] + SUM_c hma[c]*wbf2[.][256+c]
// ---------------------------------------------------------------------------
__global__ __launch_bounds__(256) void k0w_fusionw(const float* __restrict__ fw,
                                                   ushort* __restrict__ wbf2)
{
    int e = blockIdx.x * 256 + threadIdx.x;   // 256*64 = 16384
    int o = e >> 6, j = e & 63;
    const float* row = fw + (size_t)o * 512;
    float ws0 = row[j],       ws1 = row[64 + j],
          ws2 = row[128 + j], ws3 = row[192 + j];
    float wl0 = row[256 + j], wl1 = row[320 + j],
          wl2 = row[384 + j], wl3 = row[448 + j];
    float S3 = ws3, S2 = ws2 + S3, S1 = ws1 + S2, S0 = ws0 + S1;
    float L0 = wl0, L1 = L0 + wl1, L2 = L1 + wl2, L3 = L2 + wl3;
    ushort* dst = wbf2 + (size_t)o * 512;
    dst[j]        = f2b(S0); dst[64 + j]  = f2b(S1);
    dst[128 + j]  = f2b(S2); dst[192 + j] = f2b(S3);
    dst[256 + j]  = f2b(L0 - S0); dst[320 + j] = f2b(L1 - S1);
    dst[384 + j]  = f2b(L2 - S2); dst[448 + j] = f2b(L3 - S3);
}

// ---------------------------------------------------------------------------
// Kernel 0b: reorder branch conv weights [br][o][i][kk] fp32
//            -> wbr[br][o][kk*64+i] bf16  (K-major for MFMA B fragments)
// ---------------------------------------------------------------------------
__global__ __launch_bounds__(256) void k0b_convw_branch(
    const float* __restrict__ conv_w, ushort* __restrict__ wbr)
{
    int e = blockIdx.x * 256 + threadIdx.x;     // 4*64*3*64 = 49152
    int i    = e & 63;
    int rest = e >> 6;
    int kk   = rest % 3;
    int orow = rest / 3;
    float v = conv_w[(size_t)orow * 192 + i * 3 + kk];
    wbr[(size_t)orow * 192 + kk * 64 + i] = f2b(v);
}

// ---------------------------------------------------------------------------
// Kernel 0c: transpose x [B][C][L] fp32 -> xT [B][L][C] bf16
// ---------------------------------------------------------------------------
__global__ __launch_bounds__(256) void k0c_xT(const float* __restrict__ x,
                                              ushort* __restrict__ xT)
{
    const int p0    = blockIdx.x * 64;
    const int batch = blockIdx.y;
    const int tid   = threadIdx.x;

    __shared__ uint ls[256 * 33];        // [ch][33 uint] = [ch][66 ushort]

    const float* xb = x + (size_t)batch * CCH * LSEQ;
#pragma unroll
    for (int pass = 0; pass < 16; ++pass) {
        int e  = tid + pass * 256;
        int ch = e >> 4;
        int c4 = e & 15;
        float4 v = *(const float4*)&xb[(size_t)ch * LSEQ + p0 + c4 * 4];
        uint u0 = (uint)f2b(v.x) | ((uint)f2b(v.y) << 16);
        uint u1 = (uint)f2b(v.z) | ((uint)f2b(v.w) << 16);
        ls[ch * 33 + c4 * 2]     = u0;
        ls[ch * 33 + c4 * 2 + 1] = u1;
    }
    __syncthreads();

    const int w = tid >> 6, l = tid & 63;
    const ushort* lsu = (const ushort*)ls;
    ushort* dst = xT + ((size_t)batch * LSEQ + p0) * CCH;
#pragma unroll
    for (int r = 0; r < 16; ++r) {
        int p = w * 16 + r;
#pragma unroll
        for (int q = 0; q < 4; ++q) {
            int ch = l + 64 * q;
            dst[(size_t)p * CCH + ch] = lsu[ch * 66 + p];
        }
    }
}

// ---------------------------------------------------------------------------
// Kernel 1: per-branch dilated conv(k=3) as bf16 MFMA GEMM + BN + exact GELU
// Output transposed in LDS (reusing xsA) -> hT[B][L][C] bf16, coalesced drain
// ---------------------------------------------------------------------------
#define SXA 72     // LDS stride for x-tile rows (144B, 16B-aligned)
#define SWB 200    // LDS stride for w rows (400B, 16B-aligned)
__global__ __launch_bounds__(256) void k1_conv_mfma(
    const ushort* __restrict__ xT, const ushort* __restrict__ wbr,
    const float* __restrict__ conv_b, const float* __restrict__ bn_gamma,
    const float* __restrict__ bn_beta, const float* __restrict__ bn_mean,
    const float* __restrict__ bn_var, ushort* __restrict__ hT)
{
    const int tile  = blockIdx.x;
    const int br    = blockIdx.y;
    const int batch = blockIdx.z;
    const int d     = 1 << br;
    const int t0    = tile * 128;
    const int tid   = threadIdx.x;
    const int wm    = tid >> 6;
    const int lane  = tid & 63;
    const int lo    = lane & 15;
    const int hi    = lane >> 4;

    __shared__ ushort xsA[144 * SXA];
    __shared__ ushort wlB[64 * SWB];

    {
        const ushort* xTb = xT + (size_t)batch * LSEQ * CCH + br * CB;
#pragma unroll
        for (int pass = 0; pass < 5; ++pass) {
            int e = tid + pass * 256;
            int p = e >> 3;
            int c = e & 7;
            if (p < 144) {
                int gp = t0 - 8 + p;
                uint4 v = make_uint4(0u, 0u, 0u, 0u);
                if (gp >= 0 && gp < LSEQ)
                    v = *(const uint4*)&xTb[(size_t)gp * CCH + c * 8];
                *(uint4*)&xsA[p * SXA + c * 8] = v;
            }
        }
    }
    {
        const ushort* wrow = wbr + ((size_t)br * CB) * 192;
#pragma unroll
        for (int pass = 0; pass < 6; ++pass) {
            int e = tid + pass * 256;
            int o = e / 24;
            int c = e - o * 24;
            uint4 v = *(const uint4*)&wrow[e * 8];
            *(uint4*)&wlB[o * SWB + c * 8] = v;
        }
    }
    __syncthreads();

    f32x4 acc[2][4];
#pragma unroll
    for (int mi = 0; mi < 2; ++mi)
#pragma unroll
        for (int ni = 0; ni < 4; ++ni) acc[mi][ni] = (f32x4)0.f;

#pragma unroll
    for (int kk = 0; kk < 3; ++kk) {
        const int roff = 8 + (kk - 1) * d;
#pragma unroll
        for (int ks = 0; ks < 2; ++ks) {
            bf16x8 af[2], bfr[4];
#pragma unroll
            for (int mi = 0; mi < 2; ++mi)
                af[mi] = *(const bf16x8*)&xsA[
                    (wm * 32 + mi * 16 + lo + roff) * SXA + ks * 32 + hi * 8];
#pragma unroll
            for (int ni = 0; ni < 4; ++ni)
                bfr[ni] = *(const bf16x8*)&wlB[
                    (ni * 16 + lo) * SWB + kk * 64 + ks * 32 + hi * 8];
#pragma unroll
            for (int mi = 0; mi < 2; ++mi)
#pragma unroll
                for (int ni = 0; ni < 4; ++ni)
                    acc[mi][ni] = __builtin_amdgcn_mfma_f32_16x16x32_bf16(
                        af[mi], bfr[ni], acc[mi][ni], 0, 0, 0);
        }
    }

    // ---- epilogue: bias + BN + GELU -> LDS transpose (reuse xsA) -> hT ----
    __syncthreads();                       // all xsA fragment reads complete
    ushort* os = xsA;                      // [128 pos][64 ch], stride SXA
#pragma unroll
    for (int ni = 0; ni < 4; ++ni) {
        const int o  = ni * 16 + lo;
        const int go = br * CB + o;
        float bias = conv_b[go];
        float inv  = rsqrtf(bn_var[go] + BN_EPS);
        float sc   = bn_gamma[go] * inv;
        float sh   = bn_beta[go] - bn_mean[go] * sc;
#pragma unroll
        for (int mi = 0; mi < 2; ++mi) {
            const int prow = wm * 32 + mi * 16 + hi * 4;
#pragma unroll
            for (int q = 0; q < 4; ++q) {
                float v = acc[mi][ni][q] + bias;
                v = v * sc + sh;
                os[(prow + q) * SXA + o] =
                    f2b(0.5f * v * (1.f + erff(v * 0.70710678118654752f)));
            }
        }
    }
    __syncthreads();
    ushort* hTb = hT + ((size_t)batch * LSEQ + t0) * CCH + br * CB;
#pragma unroll
    for (int pass = 0; pass < 4; ++pass) {
        int e = tid + pass * 256;          // 128 rows x 8 chunks
        int r = e >> 3;
        int c = e & 7;
        *(uint4*)&hTb[(size_t)r * CCH + c * 8] = *(const uint4*)&os[r * SXA + c * 8];
    }
}

// ---------------------------------------------------------------------------
// Kernel 2: streaming 25-tap edge-clamped moving average on hT -> hmaT
// ([B][L][C] layout; running sum per channel in fp32)
// grid (32 posTiles of 128, 4 chGroups of 64, 16 batch), block 256
// ---------------------------------------------------------------------------
#define LS_S 68      // 136B rows: 8B-aligned
__global__ __launch_bounds__(256) void k2_ma(
    const ushort* __restrict__ hT, ushort* __restrict__ hmaT)
{
    const int p0    = blockIdx.x * 128;
    const int cg    = blockIdx.y;
    const int batch = blockIdx.z;
    const int tid   = threadIdx.x;

    __shared__ ushort ls[152 * LS_S];      // input rows p0-12 .. p0+139
    __shared__ ushort os[128 * LS_S];      // output rows p0 .. p0+127

    const ushort* src = hT + ((size_t)batch * LSEQ) * CCH + cg * 64;
#pragma unroll
    for (int pass = 0; pass < 10; ++pass) {
        int e = tid + pass * 256;          // 152 rows x 16 uint2-chunks
        int r = e >> 4;
        int c = e & 15;
        if (r < 152) {
            int gp = p0 - MA_H + r;
            gp = max(0, min(LSEQ - 1, gp));
            *(uint2*)&ls[r * LS_S + c * 4] = *(const uint2*)&src[(size_t)gp * CCH + c * 4];
        }
    }
    __syncthreads();

    const int ch = tid & 63;
    const int pg = tid >> 6;               // 4 groups x 32 positions
    const int r0 = pg * 32;                // ls row of first window start
    const float inv25 = 1.f / 25.f;

    float s = 0.f;
#pragma unroll
    for (int t = 0; t < 25; ++t) s += b2f(ls[(r0 + t) * LS_S + ch]);
    os[(r0 + 0) * LS_S + ch] = f2b(s * inv25);
#pragma unroll
    for (int t = 1; t < 32; ++t) {
        s += b2f(ls[(r0 + 24 + t) * LS_S + ch]) - b2f(ls[(r0 + t - 1) * LS_S + ch]);
        os[(r0 + t) * LS_S + ch] = f2b(s * inv25);
    }
    __syncthreads();

    ushort* dst = hmaT + ((size_t)batch * LSEQ + p0) * CCH + cg * 64;
#pragma unroll
    for (int pass = 0; pass < 8; ++pass) {
        int e = tid + pass * 256;          // 128 rows x 16 uint2-chunks
        int r = e >> 4;
        int c = e & 15;
        *(uint2*)&dst[(size_t)r * CCH + c * 4] = *(const uint2*)&os[r * LS_S + c * 4];
    }
}

// ---------------------------------------------------------------------------
// Kernel 3: fusion GEMM with cumsum-folded weights:
// out[pos][o] = SUM_c hT[pos][c]*W[c][o] + SUM_c hmaT[pos][c]*W[256+c][o]
// + bias + ReLU + alpha*x.  K=512: k<256 from hT, k>=256 from hmaT.
// ---------------------------------------------------------------------------
#define KTOT 512
#define SA 72
__global__ __launch_bounds__(256) void k3_fusion(
    const ushort* __restrict__ hT, const ushort* __restrict__ hmaT,
    const ushort* __restrict__ wbf2, const float* __restrict__ fb,
    const float* __restrict__ x, const float* __restrict__ alpha,
    float* __restrict__ out)
{
    const int t0    = blockIdx.x * 128;
    const int oBase = blockIdx.y * 128;
    const int batch = blockIdx.z;
    const int tid   = threadIdx.x;
    const int wid   = tid >> 6;
    const int lane  = tid & 63;
    const int lo    = lane & 15;
    const int hi    = lane >> 4;
    const int wm    = wid >> 1;
    const int wn    = wid & 1;

    __shared__ short AL[128 * SA];
    __shared__ short WL[128 * SA];

    f32x4 acc[4][4];
#pragma unroll
    for (int mi = 0; mi < 4; ++mi)
#pragma unroll
        for (int ni = 0; ni < 4; ++ni) acc[mi][ni] = (f32x4)0.f;

    const int srow = tid >> 3;
    const int scol = tid & 7;

    for (int k0 = 0; k0 < KTOT; k0 += 64) {
        const ushort* asrc = (k0 < 256)
            ? hT   + ((size_t)(batch * LSEQ + t0)) * CCH + k0
            : hmaT + ((size_t)(batch * LSEQ + t0)) * CCH + (k0 - 256);
        __syncthreads();
#pragma unroll
        for (int pass = 0; pass < 4; ++pass) {
            int row = pass * 32 + srow;
            uint4 va = *(const uint4*)&asrc[(size_t)row * CCH + scol * 8];
            *(uint4*)&AL[row * SA + scol * 8] = va;
            uint4 vw = *(const uint4*)&wbf2[
                (size_t)(oBase + row) * KTOT + k0 + scol * 8];
            *(uint4*)&WL[row * SA + scol * 8] = vw;
        }
        __syncthreads();

#pragma unroll
        for (int ks = 0; ks < 2; ++ks) {
            bf16x8 af[4], bfr[4];
#pragma unroll
            for (int mi = 0; mi < 4; ++mi)
                af[mi] = *(const bf16x8*)&AL[(wm * 64 + mi * 16 + lo) * SA + ks * 32 + hi * 8];
#pragma unroll
            for (int ni = 0; ni < 4; ++ni)
                bfr[ni] = *(const bf16x8*)&WL[(wn * 64 + ni * 16 + lo) * SA + ks * 32 + hi * 8];
#pragma unroll
            for (int mi = 0; mi < 4; ++mi)
#pragma unroll
                for (int ni = 0; ni < 4; ++ni)
                    acc[mi][ni] = __builtin_amdgcn_mfma_f32_16x16x32_bf16(
                        af[mi], bfr[ni], acc[mi][ni], 0, 0, 0);
        }
    }

    const float al = alpha[0];
#pragma unroll
    for (int ni = 0; ni < 4; ++ni) {
        const int o = oBase + wn * 64 + ni * 16 + lo;
        const float bias = fb[o];
#pragma unroll
        for (int mi = 0; mi < 4; ++mi) {
            const int pos = t0 + wm * 64 + mi * 16 + hi * 4;
            size_t base = ((size_t)(batch * CCH + o)) * LSEQ + pos;
            float4 xv = *(const float4*)&x[base];
            float4 ov;
            ov.x = fmaxf(acc[mi][ni][0] + bias, 0.f) + al * xv.x;
            ov.y = fmaxf(acc[mi][ni][1] + bias, 0.f) + al * xv.y;
            ov.z = fmaxf(acc[mi][ni][2] + bias, 0.f) + al * xv.z;
            ov.w = fmaxf(acc[mi][ni][3] + bias, 0.f) + al * xv.w;
            *(float4*)&out[base] = ov;
        }
    }
}

// ---------------------------------------------------------------------------
extern "C" void kernel_launch(void* const* d_in, const int* in_sizes, int n_in,
                              void* d_out, int out_size, void* d_ws, size_t ws_size,
                              hipStream_t stream)
{
    const float* x        = (const float*)d_in[0];
    const float* conv_w   = (const float*)d_in[1];
    const float* conv_b   = (const float*)d_in[2];
    const float* bn_gamma = (const float*)d_in[3];
    const float* bn_beta  = (const float*)d_in[4];
    const float* bn_mean  = (const float*)d_in[5];
    const float* bn_var   = (const float*)d_in[6];
    const float* fw       = (const float*)d_in[7];
    const float* fb       = (const float*)d_in[8];
    const float* alpha    = (const float*)d_in[9];
    float* out = (float*)d_out;

    ushort* hT    = (ushort*)d_ws;                                      // 32 MiB
    ushort* hmaT  = (ushort*)((char*)d_ws + (size_t)32 * 1024 * 1024);  // 32 MiB
    ushort* wbf2  = (ushort*)((char*)d_ws + (size_t)96 * 1024 * 1024);  // 256 KiB
    ushort* wbr   = (ushort*)((char*)d_ws + (size_t)97 * 1024 * 1024);  // 96 KiB
    ushort* xT    = (ushort*)((char*)d_ws + (size_t)98 * 1024 * 1024);  // 32 MiB

    k0w_fusionw<<<dim3(64), 256, 0, stream>>>(fw, wbf2);
    k0b_convw_branch<<<dim3(192), 256, 0, stream>>>(conv_w, wbr);
    k0c_xT<<<dim3(64, 16), 256, 0, stream>>>(x, xT);

    dim3 g1(32, NB, BATCH);
    k1_conv_mfma<<<g1, 256, 0, stream>>>(xT, wbr, conv_b, bn_gamma, bn_beta,
                                         bn_mean, bn_var, hT);
    dim3 g2(32, 4, BATCH);
    k2_ma<<<g2, 256, 0, stream>>>(hT, hmaT);

    dim3 g3(32, 2, BATCH);
    k3_fusion<<<g3, 256, 0, stream>>>(hT, hmaT, wbf2, fb, x, alpha, out);
}

// Round 10
// 109.663 us; speedup vs baseline: 1.3376x; 1.0398x over previous
//
#include <hip/hip_runtime.h>
#include <math.h>

#define BATCH 16
#define CCH 256
#define LSEQ 4096
#define NB 4
#define CB 64
#define MA_H 12
#define BN_EPS 1e-5f

typedef __attribute__((ext_vector_type(8))) short bf16x8;
typedef __attribute__((ext_vector_type(4))) float f32x4;

__device__ inline float b2f(ushort u) {
    union { uint i; float f; } v; v.i = ((uint)u) << 16; return v.f;
}
__device__ inline ushort f2b(float f) {   // round-to-nearest-even
    uint x = __float_as_uint(f);
    return (ushort)((x + 0x7FFFu + ((x >> 16) & 1u)) >> 16);
}

// ---------------------------------------------------------------------------
// Kernel 0w: fold the branch cumsum into the fusion weights.
// ---------------------------------------------------------------------------
__global__ __launch_bounds__(256) void k0w_fusionw(const float* __restrict__ fw,
                                                   ushort* __restrict__ wbf2)
{
    int e = blockIdx.x * 256 + threadIdx.x;   // 256*64 = 16384
    int o = e >> 6, j = e & 63;
    const float* row = fw + (size_t)o * 512;
    float ws0 = row[j],       ws1 = row[64 + j],
          ws2 = row[128 + j], ws3 = row[192 + j];
    float wl0 = row[256 + j], wl1 = row[320 + j],
          wl2 = row[384 + j], wl3 = row[448 + j];
    float S3 = ws3, S2 = ws2 + S3, S1 = ws1 + S2, S0 = ws0 + S1;
    float L0 = wl0, L1 = L0 + wl1, L2 = L1 + wl2, L3 = L2 + wl3;
    ushort* dst = wbf2 + (size_t)o * 512;
    dst[j]        = f2b(S0); dst[64 + j]  = f2b(S1);
    dst[128 + j]  = f2b(S2); dst[192 + j] = f2b(S3);
    dst[256 + j]  = f2b(L0 - S0); dst[320 + j] = f2b(L1 - S1);
    dst[384 + j]  = f2b(L2 - S2); dst[448 + j] = f2b(L3 - S3);
}

// ---------------------------------------------------------------------------
// Kernel 0b: reorder branch conv weights -> wbr[br][o][kk*64+i] bf16
// ---------------------------------------------------------------------------
__global__ __launch_bounds__(256) void k0b_convw_branch(
    const float* __restrict__ conv_w, ushort* __restrict__ wbr)
{
    int e = blockIdx.x * 256 + threadIdx.x;     // 49152
    int i    = e & 63;
    int rest = e >> 6;
    int kk   = rest % 3;
    int orow = rest / 3;
    float v = conv_w[(size_t)orow * 192 + i * 3 + kk];
    wbr[(size_t)orow * 192 + kk * 64 + i] = f2b(v);
}

// ---------------------------------------------------------------------------
// Kernel 0c: transpose x [B][C][L] fp32 -> xT [B][L][C] bf16
// ---------------------------------------------------------------------------
__global__ __launch_bounds__(256) void k0c_xT(const float* __restrict__ x,
                                              ushort* __restrict__ xT)
{
    const int p0    = blockIdx.x * 64;
    const int batch = blockIdx.y;
    const int tid   = threadIdx.x;

    __shared__ uint ls[256 * 33];

    const float* xb = x + (size_t)batch * CCH * LSEQ;
#pragma unroll
    for (int pass = 0; pass < 16; ++pass) {
        int e  = tid + pass * 256;
        int ch = e >> 4;
        int c4 = e & 15;
        float4 v = *(const float4*)&xb[(size_t)ch * LSEQ + p0 + c4 * 4];
        uint u0 = (uint)f2b(v.x) | ((uint)f2b(v.y) << 16);
        uint u1 = (uint)f2b(v.z) | ((uint)f2b(v.w) << 16);
        ls[ch * 33 + c4 * 2]     = u0;
        ls[ch * 33 + c4 * 2 + 1] = u1;
    }
    __syncthreads();

    const int w = tid >> 6, l = tid & 63;
    const ushort* lsu = (const ushort*)ls;
    ushort* dst = xT + ((size_t)batch * LSEQ + p0) * CCH;
#pragma unroll
    for (int r = 0; r < 16; ++r) {
        int p = w * 16 + r;
#pragma unroll
        for (int q = 0; q < 4; ++q) {
            int ch = l + 64 * q;
            dst[(size_t)p * CCH + ch] = lsu[ch * 66 + p];
        }
    }
}

// ---------------------------------------------------------------------------
// Kernel 1: dilated conv(k=3) MFMA GEMM + BN + GELU, MULTI-TILE:
// 4 pos-tiles per block; B + BN params staged once; next-tile A loads issued
// before the epilogue so HBM latency hides under erf.
// grid (8, 4 branches, 16 batch), block 256
// ---------------------------------------------------------------------------
#define SXA 72
#define SWB 200
#define K1T 4
__global__ __launch_bounds__(256) void k1_conv_mfma(
    const ushort* __restrict__ xT, const ushort* __restrict__ wbr,
    const float* __restrict__ conv_b, const float* __restrict__ bn_gamma,
    const float* __restrict__ bn_beta, const float* __restrict__ bn_mean,
    const float* __restrict__ bn_var, ushort* __restrict__ hT)
{
    const int br    = blockIdx.y;
    const int batch = blockIdx.z;
    const int d     = 1 << br;
    const int tid   = threadIdx.x;
    const int wm    = tid >> 6;
    const int lane  = tid & 63;
    const int lo    = lane & 15;
    const int hi    = lane >> 4;

    __shared__ ushort xsA[144 * SXA];   // A tile / reused as output transpose
    __shared__ ushort wlB[64 * SWB];

    const ushort* xTb = xT + (size_t)batch * LSEQ * CCH + br * CB;

    // ---- stage B once ----
    {
        const ushort* wrow = wbr + ((size_t)br * CB) * 192;
#pragma unroll
        for (int pass = 0; pass < 6; ++pass) {
            int e = tid + pass * 256;
            int o = e / 24;
            int c = e - o * 24;
            uint4 v = *(const uint4*)&wrow[e * 8];
            *(uint4*)&wlB[o * SWB + c * 8] = v;
        }
    }
    // ---- hoist BN params (loop-invariant) ----
    float bias[4], sc[4], sh[4];
#pragma unroll
    for (int ni = 0; ni < 4; ++ni) {
        const int go = br * CB + ni * 16 + lo;
        bias[ni] = conv_b[go];
        float inv = rsqrtf(bn_var[go] + BN_EPS);
        sc[ni] = bn_gamma[go] * inv;
        sh[ni] = bn_beta[go] - bn_mean[go] * sc[ni];
    }

    const int arow = tid >> 3;          // A-stage row slot (+k*256 rows)
    const int acol = tid & 7;
    uint4 areg[5];
    // ---- prefetch A for tile 0 ----
    {
        const int t0 = blockIdx.x * (K1T * 128);
#pragma unroll
        for (int pass = 0; pass < 5; ++pass) {
            int p = arow + pass * 32;
            areg[pass] = make_uint4(0u, 0u, 0u, 0u);
            if (p < 144) {
                int gp = t0 - 8 + p;
                if (gp >= 0 && gp < LSEQ)
                    areg[pass] = *(const uint4*)&xTb[(size_t)gp * CCH + acol * 8];
            }
        }
    }

    for (int t = 0; t < K1T; ++t) {
        const int t0 = blockIdx.x * (K1T * 128) + t * 128;
        __syncthreads();                 // xsA free (drained / initial)
#pragma unroll
        for (int pass = 0; pass < 5; ++pass) {
            int p = arow + pass * 32;
            if (p < 144) *(uint4*)&xsA[p * SXA + acol * 8] = areg[pass];
        }
        __syncthreads();

        f32x4 acc[2][4];
#pragma unroll
        for (int mi = 0; mi < 2; ++mi)
#pragma unroll
            for (int ni = 0; ni < 4; ++ni) acc[mi][ni] = (f32x4)0.f;

#pragma unroll
        for (int kk = 0; kk < 3; ++kk) {
            const int roff = 8 + (kk - 1) * d;
#pragma unroll
            for (int ks = 0; ks < 2; ++ks) {
                bf16x8 af[2], bfr[4];
#pragma unroll
                for (int mi = 0; mi < 2; ++mi)
                    af[mi] = *(const bf16x8*)&xsA[
                        (wm * 32 + mi * 16 + lo + roff) * SXA + ks * 32 + hi * 8];
#pragma unroll
                for (int ni = 0; ni < 4; ++ni)
                    bfr[ni] = *(const bf16x8*)&wlB[
                        (ni * 16 + lo) * SWB + kk * 64 + ks * 32 + hi * 8];
#pragma unroll
                for (int mi = 0; mi < 2; ++mi)
#pragma unroll
                    for (int ni = 0; ni < 4; ++ni)
                        acc[mi][ni] = __builtin_amdgcn_mfma_f32_16x16x32_bf16(
                            af[mi], bfr[ni], acc[mi][ni], 0, 0, 0);
            }
        }

        // ---- issue next tile's A loads (latency hides under epilogue) ----
        if (t + 1 < K1T) {
            const int tn = t0 + 128;
#pragma unroll
            for (int pass = 0; pass < 5; ++pass) {
                int p = arow + pass * 32;
                areg[pass] = make_uint4(0u, 0u, 0u, 0u);
                if (p < 144) {
                    int gp = tn - 8 + p;
                    if (gp >= 0 && gp < LSEQ)
                        areg[pass] = *(const uint4*)&xTb[(size_t)gp * CCH + acol * 8];
                }
            }
        }

        __syncthreads();                 // all MFMA reads of xsA complete
        ushort* os = xsA;                // reuse as [128 pos][64 ch]
#pragma unroll
        for (int ni = 0; ni < 4; ++ni) {
            const int o = ni * 16 + lo;
#pragma unroll
            for (int mi = 0; mi < 2; ++mi) {
                const int prow = wm * 32 + mi * 16 + hi * 4;
#pragma unroll
                for (int q = 0; q < 4; ++q) {
                    float v = acc[mi][ni][q] + bias[ni];
                    v = v * sc[ni] + sh[ni];
                    os[(prow + q) * SXA + o] =
                        f2b(0.5f * v * (1.f + erff(v * 0.70710678118654752f)));
                }
            }
        }
        __syncthreads();
        ushort* hTb = hT + ((size_t)batch * LSEQ + t0) * CCH + br * CB;
#pragma unroll
        for (int pass = 0; pass < 4; ++pass) {
            int e = tid + pass * 256;
            int r = e >> 3;
            int c = e & 7;
            *(uint4*)&hTb[(size_t)r * CCH + c * 8] = *(const uint4*)&xsA[r * SXA + c * 8];
        }
    }
}

// ---------------------------------------------------------------------------
// Kernel 2: streaming 25-tap edge-clamped moving average on hT -> hmaT
// ---------------------------------------------------------------------------
#define LS_S 68
__global__ __launch_bounds__(256) void k2_ma(
    const ushort* __restrict__ hT, ushort* __restrict__ hmaT)
{
    const int p0    = blockIdx.x * 128;
    const int cg    = blockIdx.y;
    const int batch = blockIdx.z;
    const int tid   = threadIdx.x;

    __shared__ ushort ls[152 * LS_S];
    __shared__ ushort os[128 * LS_S];

    const ushort* src = hT + ((size_t)batch * LSEQ) * CCH + cg * 64;
#pragma unroll
    for (int pass = 0; pass < 10; ++pass) {
        int e = tid + pass * 256;
        int r = e >> 4;
        int c = e & 15;
        if (r < 152) {
            int gp = p0 - MA_H + r;
            gp = max(0, min(LSEQ - 1, gp));
            *(uint2*)&ls[r * LS_S + c * 4] = *(const uint2*)&src[(size_t)gp * CCH + c * 4];
        }
    }
    __syncthreads();

    const int ch = tid & 63;
    const int pg = tid >> 6;
    const int r0 = pg * 32;
    const float inv25 = 1.f / 25.f;

    float s = 0.f;
#pragma unroll
    for (int t = 0; t < 25; ++t) s += b2f(ls[(r0 + t) * LS_S + ch]);
    os[(r0 + 0) * LS_S + ch] = f2b(s * inv25);
#pragma unroll
    for (int t = 1; t < 32; ++t) {
        s += b2f(ls[(r0 + 24 + t) * LS_S + ch]) - b2f(ls[(r0 + t - 1) * LS_S + ch]);
        os[(r0 + t) * LS_S + ch] = f2b(s * inv25);
    }
    __syncthreads();

    ushort* dst = hmaT + ((size_t)batch * LSEQ + p0) * CCH + cg * 64;
#pragma unroll
    for (int pass = 0; pass < 8; ++pass) {
        int e = tid + pass * 256;
        int r = e >> 4;
        int c = e & 15;
        *(uint2*)&dst[(size_t)r * CCH + c * 4] = *(const uint2*)&os[r * LS_S + c * 4];
    }
}

// ---------------------------------------------------------------------------
// Kernel 3: fusion GEMM (cumsum-folded weights) + bias + ReLU + alpha*x
// ---------------------------------------------------------------------------
#define KTOT 512
#define SA 72
__global__ __launch_bounds__(256) void k3_fusion(
    const ushort* __restrict__ hT, const ushort* __restrict__ hmaT,
    const ushort* __restrict__ wbf2, const float* __restrict__ fb,
    const float* __restrict__ x, const float* __restrict__ alpha,
    float* __restrict__ out)
{
    const int t0    = blockIdx.x * 128;
    const int oBase = blockIdx.y * 128;
    const int batch = blockIdx.z;
    const int tid   = threadIdx.x;
    const int wid   = tid >> 6;
    const int lane  = tid & 63;
    const int lo    = lane & 15;
    const int hi    = lane >> 4;
    const int wm    = wid >> 1;
    const int wn    = wid & 1;

    __shared__ short AL[128 * SA];
    __shared__ short WL[128 * SA];

    f32x4 acc[4][4];
#pragma unroll
    for (int mi = 0; mi < 4; ++mi)
#pragma unroll
        for (int ni = 0; ni < 4; ++ni) acc[mi][ni] = (f32x4)0.f;

    const int srow = tid >> 3;
    const int scol = tid & 7;

    for (int k0 = 0; k0 < KTOT; k0 += 64) {
        const ushort* asrc = (k0 < 256)
            ? hT   + ((size_t)(batch * LSEQ + t0)) * CCH + k0
            : hmaT + ((size_t)(batch * LSEQ + t0)) * CCH + (k0 - 256);
        __syncthreads();
#pragma unroll
        for (int pass = 0; pass < 4; ++pass) {
            int row = pass * 32 + srow;
            uint4 va = *(const uint4*)&asrc[(size_t)row * CCH + scol * 8];
            *(uint4*)&AL[row * SA + scol * 8] = va;
            uint4 vw = *(const uint4*)&wbf2[
                (size_t)(oBase + row) * KTOT + k0 + scol * 8];
            *(uint4*)&WL[row * SA + scol * 8] = vw;
        }
        __syncthreads();

#pragma unroll
        for (int ks = 0; ks < 2; ++ks) {
            bf16x8 af[4], bfr[4];
#pragma unroll
            for (int mi = 0; mi < 4; ++mi)
                af[mi] = *(const bf16x8*)&AL[(wm * 64 + mi * 16 + lo) * SA + ks * 32 + hi * 8];
#pragma unroll
            for (int ni = 0; ni < 4; ++ni)
                bfr[ni] = *(const bf16x8*)&WL[(wn * 64 + ni * 16 + lo) * SA + ks * 32 + hi * 8];
#pragma unroll
            for (int mi = 0; mi < 4; ++mi)
#pragma unroll
                for (int ni = 0; ni < 4; ++ni)
                    acc[mi][ni] = __builtin_amdgcn_mfma_f32_16x16x32_bf16(
                        af[mi], bfr[ni], acc[mi][ni], 0, 0, 0);
        }
    }

    const float al = alpha[0];
#pragma unroll
    for (int ni = 0; ni < 4; ++ni) {
        const int o = oBase + wn * 64 + ni * 16 + lo;
        const float bias = fb[o];
#pragma unroll
        for (int mi = 0; mi < 4; ++mi) {
            const int pos = t0 + wm * 64 + mi * 16 + hi * 4;
            size_t base = ((size_t)(batch * CCH + o)) * LSEQ + pos;
            float4 xv = *(const float4*)&x[base];
            float4 ov;
            ov.x = fmaxf(acc[mi][ni][0] + bias, 0.f) + al * xv.x;
            ov.y = fmaxf(acc[mi][ni][1] + bias, 0.f) + al * xv.y;
            ov.z = fmaxf(acc[mi][ni][2] + bias, 0.f) + al * xv.z;
            ov.w = fmaxf(acc[mi][ni][3] + bias, 0.f) + al * xv.w;
            *(float4*)&out[base] = ov;
        }
    }
}

// ---------------------------------------------------------------------------
extern "C" void kernel_launch(void* const* d_in, const int* in_sizes, int n_in,
                              void* d_out, int out_size, void* d_ws, size_t ws_size,
                              hipStream_t stream)
{
    const float* x        = (const float*)d_in[0];
    const float* conv_w   = (const float*)d_in[1];
    const float* conv_b   = (const float*)d_in[2];
    const float* bn_gamma = (const float*)d_in[3];
    const float* bn_beta  = (const float*)d_in[4];
    const float* bn_mean  = (const float*)d_in[5];
    const float* bn_var   = (const float*)d_in[6];
    const float* fw       = (const float*)d_in[7];
    const float* fb       = (const float*)d_in[8];
    const float* alpha    = (const float*)d_in[9];
    float* out = (float*)d_out;

    ushort* hT    = (ushort*)d_ws;                                      // 32 MiB
    ushort* hmaT  = (ushort*)((char*)d_ws + (size_t)32 * 1024 * 1024);  // 32 MiB
    ushort* wbf2  = (ushort*)((char*)d_ws + (size_t)96 * 1024 * 1024);  // 256 KiB
    ushort* wbr   = (ushort*)((char*)d_ws + (size_t)97 * 1024 * 1024);  // 96 KiB
    ushort* xT    = (ushort*)((char*)d_ws + (size_t)98 * 1024 * 1024);  // 32 MiB

    k0w_fusionw<<<dim3(64), 256, 0, stream>>>(fw, wbf2);
    k0b_convw_branch<<<dim3(192), 256, 0, stream>>>(conv_w, wbr);
    k0c_xT<<<dim3(64, 16), 256, 0, stream>>>(x, xT);

    dim3 g1(8, NB, BATCH);
    k1_conv_mfma<<<g1, 256, 0, stream>>>(xT, wbr, conv_b, bn_gamma, bn_beta,
                                         bn_mean, bn_var, hT);
    dim3 g2(32, 4, BATCH);
    k2_ma<<<g2, 256, 0, stream>>>(hT, hmaT);

    dim3 g3(32, 2, BATCH);
    k3_fusion<<<g3, 256, 0, stream>>>(hT, hmaT, wbf2, fb, x, alpha, out);
}

// Round 11
// 106.505 us; speedup vs baseline: 1.3772x; 1.0296x over previous
//
#include <hip/hip_runtime.h>
#include <math.h>

#define BATCH 16
#define CCH 256
#define LSEQ 4096
#define NB 4
#define CB 64
#define MA_H 12
#define BN_EPS 1e-5f

typedef __attribute__((ext_vector_type(8))) short bf16x8;
typedef __attribute__((ext_vector_type(4))) float f32x4;

__device__ inline float b2f(ushort u) {
    union { uint i; float f; } v; v.i = ((uint)u) << 16; return v.f;
}
__device__ inline ushort f2b(float f) {   // round-to-nearest-even
    uint x = __float_as_uint(f);
    return (ushort)((x + 0x7FFFu + ((x >> 16) & 1u)) >> 16);
}
// branch-free tanh-form GELU (max |err| vs exact-erf GELU ~3e-4, << bf16 quantum)
__device__ inline float gelu_fast(float v) {
    float t2 = fmaf(0.044715f, v * v, 1.f);
    float u2 = 1.59576912160573f * v * t2;     // 2*sqrt(2/pi)*(v+0.044715v^3)
    float e  = __expf(u2);
    float r  = __frcp_rn(e + 1.f);
    return v * (1.f - r);                       // = 0.5v(1+tanh(u))
}

// ---------------------------------------------------------------------------
// Kernel 0w: fold the branch cumsum into the fusion weights.
// ---------------------------------------------------------------------------
__global__ __launch_bounds__(256) void k0w_fusionw(const float* __restrict__ fw,
                                                   ushort* __restrict__ wbf2)
{
    int e = blockIdx.x * 256 + threadIdx.x;   // 256*64 = 16384
    int o = e >> 6, j = e & 63;
    const float* row = fw + (size_t)o * 512;
    float ws0 = row[j],       ws1 = row[64 + j],
          ws2 = row[128 + j], ws3 = row[192 + j];
    float wl0 = row[256 + j], wl1 = row[320 + j],
          wl2 = row[384 + j], wl3 = row[448 + j];
    float S3 = ws3, S2 = ws2 + S3, S1 = ws1 + S2, S0 = ws0 + S1;
    float L0 = wl0, L1 = L0 + wl1, L2 = L1 + wl2, L3 = L2 + wl3;
    ushort* dst = wbf2 + (size_t)o * 512;
    dst[j]        = f2b(S0); dst[64 + j]  = f2b(S1);
    dst[128 + j]  = f2b(S2); dst[192 + j] = f2b(S3);
    dst[256 + j]  = f2b(L0 - S0); dst[320 + j] = f2b(L1 - S1);
    dst[384 + j]  = f2b(L2 - S2); dst[448 + j] = f2b(L3 - S3);
}

// ---------------------------------------------------------------------------
// Kernel 0b: reorder branch conv weights -> wbr[br][o][kk*64+i] bf16
// ---------------------------------------------------------------------------
__global__ __launch_bounds__(256) void k0b_convw_branch(
    const float* __restrict__ conv_w, ushort* __restrict__ wbr)
{
    int e = blockIdx.x * 256 + threadIdx.x;     // 49152
    int i    = e & 63;
    int rest = e >> 6;
    int kk   = rest % 3;
    int orow = rest / 3;
    float v = conv_w[(size_t)orow * 192 + i * 3 + kk];
    wbr[(size_t)orow * 192 + kk * 64 + i] = f2b(v);
}

// ---------------------------------------------------------------------------
// Kernel 0c: transpose x [B][C][L] fp32 -> xT [B][L][C] bf16
// ---------------------------------------------------------------------------
__global__ __launch_bounds__(256) void k0c_xT(const float* __restrict__ x,
                                              ushort* __restrict__ xT)
{
    const int p0    = blockIdx.x * 64;
    const int batch = blockIdx.y;
    const int tid   = threadIdx.x;

    __shared__ uint ls[256 * 33];

    const float* xb = x + (size_t)batch * CCH * LSEQ;
#pragma unroll
    for (int pass = 0; pass < 16; ++pass) {
        int e  = tid + pass * 256;
        int ch = e >> 4;
        int c4 = e & 15;
        float4 v = *(const float4*)&xb[(size_t)ch * LSEQ + p0 + c4 * 4];
        uint u0 = (uint)f2b(v.x) | ((uint)f2b(v.y) << 16);
        uint u1 = (uint)f2b(v.z) | ((uint)f2b(v.w) << 16);
        ls[ch * 33 + c4 * 2]     = u0;
        ls[ch * 33 + c4 * 2 + 1] = u1;
    }
    __syncthreads();

    const int w = tid >> 6, l = tid & 63;
    const ushort* lsu = (const ushort*)ls;
    ushort* dst = xT + ((size_t)batch * LSEQ + p0) * CCH;
#pragma unroll
    for (int r = 0; r < 16; ++r) {
        int p = w * 16 + r;
#pragma unroll
        for (int q = 0; q < 4; ++q) {
            int ch = l + 64 * q;
            dst[(size_t)p * CCH + ch] = lsu[ch * 66 + p];
        }
    }
}

// ---------------------------------------------------------------------------
// Kernel 1: dilated conv(k=3) MFMA GEMM + BN + fast GELU, multi-tile.
// grid (8, 4 branches, 16 batch), block 256
// ---------------------------------------------------------------------------
#define SXA 72
#define SWB 200
#define K1T 4
__global__ __launch_bounds__(256) void k1_conv_mfma(
    const ushort* __restrict__ xT, const ushort* __restrict__ wbr,
    const float* __restrict__ conv_b, const float* __restrict__ bn_gamma,
    const float* __restrict__ bn_beta, const float* __restrict__ bn_mean,
    const float* __restrict__ bn_var, ushort* __restrict__ hT)
{
    const int br    = blockIdx.y;
    const int batch = blockIdx.z;
    const int d     = 1 << br;
    const int tid   = threadIdx.x;
    const int wm    = tid >> 6;
    const int lane  = tid & 63;
    const int lo    = lane & 15;
    const int hi    = lane >> 4;

    __shared__ ushort xsA[144 * SXA];   // A tile / reused as output transpose
    __shared__ ushort wlB[64 * SWB];

    const ushort* xTb = xT + (size_t)batch * LSEQ * CCH + br * CB;

    // ---- stage B once ----
    {
        const ushort* wrow = wbr + ((size_t)br * CB) * 192;
#pragma unroll
        for (int pass = 0; pass < 6; ++pass) {
            int e = tid + pass * 256;
            int o = e / 24;
            int c = e - o * 24;
            uint4 v = *(const uint4*)&wrow[e * 8];
            *(uint4*)&wlB[o * SWB + c * 8] = v;
        }
    }
    // ---- hoist BN params (loop-invariant) ----
    float bias[4], sc[4], sh[4];
#pragma unroll
    for (int ni = 0; ni < 4; ++ni) {
        const int go = br * CB + ni * 16 + lo;
        bias[ni] = conv_b[go];
        float inv = rsqrtf(bn_var[go] + BN_EPS);
        sc[ni] = bn_gamma[go] * inv;
        sh[ni] = bn_beta[go] - bn_mean[go] * sc[ni];
    }

    const int arow = tid >> 3;
    const int acol = tid & 7;
    uint4 areg[5];
    {
        const int t0 = blockIdx.x * (K1T * 128);
#pragma unroll
        for (int pass = 0; pass < 5; ++pass) {
            int p = arow + pass * 32;
            areg[pass] = make_uint4(0u, 0u, 0u, 0u);
            if (p < 144) {
                int gp = t0 - 8 + p;
                if (gp >= 0 && gp < LSEQ)
                    areg[pass] = *(const uint4*)&xTb[(size_t)gp * CCH + acol * 8];
            }
        }
    }

    for (int t = 0; t < K1T; ++t) {
        const int t0 = blockIdx.x * (K1T * 128) + t * 128;
        __syncthreads();
#pragma unroll
        for (int pass = 0; pass < 5; ++pass) {
            int p = arow + pass * 32;
            if (p < 144) *(uint4*)&xsA[p * SXA + acol * 8] = areg[pass];
        }
        __syncthreads();

        f32x4 acc[2][4];
#pragma unroll
        for (int mi = 0; mi < 2; ++mi)
#pragma unroll
            for (int ni = 0; ni < 4; ++ni) acc[mi][ni] = (f32x4)0.f;

#pragma unroll
        for (int kk = 0; kk < 3; ++kk) {
            const int roff = 8 + (kk - 1) * d;
#pragma unroll
            for (int ks = 0; ks < 2; ++ks) {
                bf16x8 af[2], bfr[4];
#pragma unroll
                for (int mi = 0; mi < 2; ++mi)
                    af[mi] = *(const bf16x8*)&xsA[
                        (wm * 32 + mi * 16 + lo + roff) * SXA + ks * 32 + hi * 8];
#pragma unroll
                for (int ni = 0; ni < 4; ++ni)
                    bfr[ni] = *(const bf16x8*)&wlB[
                        (ni * 16 + lo) * SWB + kk * 64 + ks * 32 + hi * 8];
#pragma unroll
                for (int mi = 0; mi < 2; ++mi)
#pragma unroll
                    for (int ni = 0; ni < 4; ++ni)
                        acc[mi][ni] = __builtin_amdgcn_mfma_f32_16x16x32_bf16(
                            af[mi], bfr[ni], acc[mi][ni], 0, 0, 0);
            }
        }

        // ---- issue next tile's A loads (latency hides under epilogue) ----
        if (t + 1 < K1T) {
            const int tn = t0 + 128;
#pragma unroll
            for (int pass = 0; pass < 5; ++pass) {
                int p = arow + pass * 32;
                areg[pass] = make_uint4(0u, 0u, 0u, 0u);
                if (p < 144) {
                    int gp = tn - 8 + p;
                    if (gp >= 0 && gp < LSEQ)
                        areg[pass] = *(const uint4*)&xTb[(size_t)gp * CCH + acol * 8];
                }
            }
        }

        __syncthreads();
        ushort* os = xsA;                // reuse as [128 pos][64 ch]
#pragma unroll
        for (int ni = 0; ni < 4; ++ni) {
            const int o = ni * 16 + lo;
#pragma unroll
            for (int mi = 0; mi < 2; ++mi) {
                const int prow = wm * 32 + mi * 16 + hi * 4;
#pragma unroll
                for (int q = 0; q < 4; ++q) {
                    float v = acc[mi][ni][q] + bias[ni];
                    v = v * sc[ni] + sh[ni];
                    os[(prow + q) * SXA + o] = f2b(gelu_fast(v));
                }
            }
        }
        __syncthreads();
        ushort* hTb = hT + ((size_t)batch * LSEQ + t0) * CCH + br * CB;
#pragma unroll
        for (int pass = 0; pass < 4; ++pass) {
            int e = tid + pass * 256;
            int r = e >> 3;
            int c = e & 7;
            *(uint4*)&hTb[(size_t)r * CCH + c * 8] = *(const uint4*)&xsA[r * SXA + c * 8];
        }
    }
}

// ---------------------------------------------------------------------------
// Kernel 2: streaming 25-tap edge-clamped moving average on hT -> hmaT
// ---------------------------------------------------------------------------
#define LS_S 68
__global__ __launch_bounds__(256) void k2_ma(
    const ushort* __restrict__ hT, ushort* __restrict__ hmaT)
{
    const int p0    = blockIdx.x * 128;
    const int cg    = blockIdx.y;
    const int batch = blockIdx.z;
    const int tid   = threadIdx.x;

    __shared__ ushort ls[152 * LS_S];
    __shared__ ushort os[128 * LS_S];

    const ushort* src = hT + ((size_t)batch * LSEQ) * CCH + cg * 64;
#pragma unroll
    for (int pass = 0; pass < 10; ++pass) {
        int e = tid + pass * 256;
        int r = e >> 4;
        int c = e & 15;
        if (r < 152) {
            int gp = p0 - MA_H + r;
            gp = max(0, min(LSEQ - 1, gp));
            *(uint2*)&ls[r * LS_S + c * 4] = *(const uint2*)&src[(size_t)gp * CCH + c * 4];
        }
    }
    __syncthreads();

    const int ch = tid & 63;
    const int pg = tid >> 6;
    const int r0 = pg * 32;
    const float inv25 = 1.f / 25.f;

    float s = 0.f;
#pragma unroll
    for (int t = 0; t < 25; ++t) s += b2f(ls[(r0 + t) * LS_S + ch]);
    os[(r0 + 0) * LS_S + ch] = f2b(s * inv25);
#pragma unroll
    for (int t = 1; t < 32; ++t) {
        s += b2f(ls[(r0 + 24 + t) * LS_S + ch]) - b2f(ls[(r0 + t - 1) * LS_S + ch]);
        os[(r0 + t) * LS_S + ch] = f2b(s * inv25);
    }
    __syncthreads();

    ushort* dst = hmaT + ((size_t)batch * LSEQ + p0) * CCH + cg * 64;
#pragma unroll
    for (int pass = 0; pass < 8; ++pass) {
        int e = tid + pass * 256;
        int r = e >> 4;
        int c = e & 15;
        *(uint2*)&dst[(size_t)r * CCH + c * 4] = *(const uint2*)&os[r * LS_S + c * 4];
    }
}

// ---------------------------------------------------------------------------
// Kernel 3: fusion GEMM (cumsum-folded weights) + bias + ReLU + alpha*x
// ---------------------------------------------------------------------------
#define KTOT 512
#define SA 72
__global__ __launch_bounds__(256) void k3_fusion(
    const ushort* __restrict__ hT, const ushort* __restrict__ hmaT,
    const ushort* __restrict__ wbf2, const float* __restrict__ fb,
    const float* __restrict__ x, const float* __restrict__ alpha,
    float* __restrict__ out)
{
    const int t0    = blockIdx.x * 128;
    const int oBase = blockIdx.y * 128;
    const int batch = blockIdx.z;
    const int tid   = threadIdx.x;
    const int wid   = tid >> 6;
    const int lane  = tid & 63;
    const int lo    = lane & 15;
    const int hi    = lane >> 4;
    const int wm    = wid >> 1;
    const int wn    = wid & 1;

    __shared__ short AL[128 * SA];
    __shared__ short WL[128 * SA];

    f32x4 acc[4][4];
#pragma unroll
    for (int mi = 0; mi < 4; ++mi)
#pragma unroll
        for (int ni = 0; ni < 4; ++ni) acc[mi][ni] = (f32x4)0.f;

    const int srow = tid >> 3;
    const int scol = tid & 7;

    for (int k0 = 0; k0 < KTOT; k0 += 64) {
        const ushort* asrc = (k0 < 256)
            ? hT   + ((size_t)(batch * LSEQ + t0)) * CCH + k0
            : hmaT + ((size_t)(batch * LSEQ + t0)) * CCH + (k0 - 256);
        __syncthreads();
#pragma unroll
        for (int pass = 0; pass < 4; ++pass) {
            int row = pass * 32 + srow;
            uint4 va = *(const uint4*)&asrc[(size_t)row * CCH + scol * 8];
            *(uint4*)&AL[row * SA + scol * 8] = va;
            uint4 vw = *(const uint4*)&wbf2[
                (size_t)(oBase + row) * KTOT + k0 + scol * 8];
            *(uint4*)&WL[row * SA + scol * 8] = vw;
        }
        __syncthreads();

#pragma unroll
        for (int ks = 0; ks < 2; ++ks) {
            bf16x8 af[4], bfr[4];
#pragma unroll
            for (int mi = 0; mi < 4; ++mi)
                af[mi] = *(const bf16x8*)&AL[(wm * 64 + mi * 16 + lo) * SA + ks * 32 + hi * 8];
#pragma unroll
            for (int ni = 0; ni < 4; ++ni)
                bfr[ni] = *(const bf16x8*)&WL[(wn * 64 + ni * 16 + lo) * SA + ks * 32 + hi * 8];
#pragma unroll
            for (int mi = 0; mi < 4; ++mi)
#pragma unroll
                for (int ni = 0; ni < 4; ++ni)
                    acc[mi][ni] = __builtin_amdgcn_mfma_f32_16x16x32_bf16(
                        af[mi], bfr[ni], acc[mi][ni], 0, 0, 0);
        }
    }

    const float al = alpha[0];
#pragma unroll
    for (int ni = 0; ni < 4; ++ni) {
        const int o = oBase + wn * 64 + ni * 16 + lo;
        const float bias = fb[o];
#pragma unroll
        for (int mi = 0; mi < 4; ++mi) {
            const int pos = t0 + wm * 64 + mi * 16 + hi * 4;
            size_t base = ((size_t)(batch * CCH + o)) * LSEQ + pos;
            float4 xv = *(const float4*)&x[base];
            float4 ov;
            ov.x = fmaxf(acc[mi][ni][0] + bias, 0.f) + al * xv.x;
            ov.y = fmaxf(acc[mi][ni][1] + bias, 0.f) + al * xv.y;
            ov.z = fmaxf(acc[mi][ni][2] + bias, 0.f) + al * xv.z;
            ov.w = fmaxf(acc[mi][ni][3] + bias, 0.f) + al * xv.w;
            *(float4*)&out[base] = ov;
        }
    }
}

// ---------------------------------------------------------------------------
extern "C" void kernel_launch(void* const* d_in, const int* in_sizes, int n_in,
                              void* d_out, int out_size, void* d_ws, size_t ws_size,
                              hipStream_t stream)
{
    const float* x        = (const float*)d_in[0];
    const float* conv_w   = (const float*)d_in[1];
    const float* conv_b   = (const float*)d_in[2];
    const float* bn_gamma = (const float*)d_in[3];
    const float* bn_beta  = (const float*)d_in[4];
    const float* bn_mean  = (const float*)d_in[5];
    const float* bn_var   = (const float*)d_in[6];
    const float* fw       = (const float*)d_in[7];
    const float* fb       = (const float*)d_in[8];
    const float* alpha    = (const float*)d_in[9];
    float* out = (float*)d_out;

    ushort* hT    = (ushort*)d_ws;                                      // 32 MiB
    ushort* hmaT  = (ushort*)((char*)d_ws + (size_t)32 * 1024 * 1024);  // 32 MiB
    ushort* wbf2  = (ushort*)((char*)d_ws + (size_t)96 * 1024 * 1024);  // 256 KiB
    ushort* wbr   = (ushort*)((char*)d_ws + (size_t)97 * 1024 * 1024);  // 96 KiB
    ushort* xT    = (ushort*)((char*)d_ws + (size_t)98 * 1024 * 1024);  // 32 MiB

    k0w_fusionw<<<dim3(64), 256, 0, stream>>>(fw, wbf2);
    k0b_convw_branch<<<dim3(192), 256, 0, stream>>>(conv_w, wbr);
    k0c_xT<<<dim3(64, 16), 256, 0, stream>>>(x, xT);

    dim3 g1(8, NB, BATCH);
    k1_conv_mfma<<<g1, 256, 0, stream>>>(xT, wbr, conv_b, bn_gamma, bn_beta,
                                         bn_mean, bn_var, hT);
    dim3 g2(32, 4, BATCH);
    k2_ma<<<g2, 256, 0, stream>>>(hT, hmaT);

    dim3 g3(32, 2, BATCH);
    k3_fusion<<<g3, 256, 0, stream>>>(hT, hmaT, wbf2, fb, x, alpha, out);
}